// Round 1
// baseline (158.828 us; speedup 1.0000x reference)
//
#include <hip/hip_runtime.h>

// EdgeSumAggregatorSparse: out[b, t[e], d] += msgs[b, e, d]
// B=2, D=128 hard-coded (derived-checked from sizes); E, N derived at launch.

#define D_DIM 128
#define B_DIM 2
#define MAX_CAP 256

// ---------------------------------------------------------------- zero pass
__global__ void zero_kernel(float* __restrict__ out, size_t out_elems,
                            int* __restrict__ counts, int n_counts) {
    size_t i = (size_t)blockIdx.x * blockDim.x + threadIdx.x;
    size_t stride = (size_t)gridDim.x * blockDim.x;
    for (size_t j = i; j < out_elems; j += stride) out[j] = 0.0f;
    for (size_t j = i; j < (size_t)n_counts; j += stride) counts[j] = 0;
}

// ------------------------------------------------------------- bucket fill
// One thread per edge. Claims a slot in its target node's bucket via an int
// atomic. Overflow (> cap edges on one node) falls back to direct fp32
// atomics into out — correct for any input, ~never taken at cap=256, lambda=50.
__global__ void bucket_fill_kernel(const int* __restrict__ targets,
                                   const float* __restrict__ msgs,
                                   float* __restrict__ out,
                                   int* __restrict__ counts,
                                   int* __restrict__ buckets,
                                   int E, int N, int cap) {
    int e = blockIdx.x * blockDim.x + threadIdx.x;
    if (e >= E) return;
    int t = targets[e];
    int pos = atomicAdd(&counts[t], 1);
    if (pos < cap) {
        buckets[(size_t)t * cap + pos] = e;
    } else {
        // rare overflow path: direct scatter-add
        for (int b = 0; b < B_DIM; ++b) {
            const float* src = msgs + ((size_t)b * E + e) * D_DIM;
            float* dst = out + ((size_t)b * N + t) * D_DIM;
            for (int d = 0; d < D_DIM; ++d) atomicAdd(&dst[d], src[d]);
        }
    }
}

// ------------------------------------------------------------------ gather
// One block (64 threads = 1 wave) per node.
// lanes 0..31  -> batch 0, float4 slice q = lane
// lanes 32..63 -> batch 1, float4 slice q = lane-32
// Each bucket entry drives one fully-coalesced 512B row read per batch.
__global__ __launch_bounds__(64) void gather_kernel(
        const float* __restrict__ msgs,
        const int* __restrict__ counts,
        const int* __restrict__ buckets,
        float* __restrict__ out,
        int E, int N, int cap) {
    int n = blockIdx.x;
    int tid = threadIdx.x;
    int b = tid >> 5;    // batch
    int q = tid & 31;    // float4 slot within the 128-float row

    int cnt = counts[n];
    if (cnt > cap) cnt = cap;
    const int* bk = buckets + (size_t)n * cap;

    float4 acc = make_float4(0.f, 0.f, 0.f, 0.f);
    const size_t batch_off = (size_t)b * E * D_DIM;
    for (int i = 0; i < cnt; ++i) {
        int e = bk[i];  // uniform across the wave -> broadcast
        const float4* row = reinterpret_cast<const float4*>(msgs + batch_off + (size_t)e * D_DIM);
        float4 v = row[q];
        acc.x += v.x; acc.y += v.y; acc.z += v.z; acc.w += v.w;
    }

    // out may already hold overflow-path contributions; single writer here.
    float4* o = reinterpret_cast<float4*>(out + ((size_t)b * N + n) * D_DIM) + q;
    float4 cur = *o;
    cur.x += acc.x; cur.y += acc.y; cur.z += acc.z; cur.w += acc.w;
    *o = cur;
}

// --------------------------------------------------- fallback: pure atomics
// Used only if d_ws is too small for buckets (shouldn't happen).
__global__ void scatter_atomic_kernel(const float* __restrict__ msgs,
                                      const int* __restrict__ targets,
                                      float* __restrict__ out,
                                      int E, int N) {
    size_t total = (size_t)E * D_DIM;
    size_t stride = (size_t)gridDim.x * blockDim.x;
    for (size_t idx = (size_t)blockIdx.x * blockDim.x + threadIdx.x;
         idx < total; idx += stride) {
        int e = (int)(idx >> 7);
        int d = (int)(idx & (D_DIM - 1));
        int t = targets[e];
        atomicAdd(&out[((size_t)0 * N + t) * D_DIM + d],
                  msgs[((size_t)0 * E + e) * D_DIM + d]);
        atomicAdd(&out[((size_t)1 * N + t) * D_DIM + d],
                  msgs[((size_t)1 * E + e) * D_DIM + d]);
    }
}

extern "C" void kernel_launch(void* const* d_in, const int* in_sizes, int n_in,
                              void* d_out, int out_size, void* d_ws, size_t ws_size,
                              hipStream_t stream) {
    const float* msgs    = (const float*)d_in[0];
    const int*   targets = (const int*)d_in[1];
    float*       out     = (float*)d_out;

    const int E = in_sizes[1];
    const int N = out_size / (B_DIM * D_DIM);

    // workspace layout: [ counts: N ints ][ buckets: N*cap ints ]
    size_t ws_ints = ws_size / sizeof(int);
    long cap_l = ((long)ws_ints - N) / (N > 0 ? N : 1);
    int cap = (int)(cap_l < 0 ? 0 : (cap_l > MAX_CAP ? MAX_CAP : cap_l));

    size_t out_elems = (size_t)out_size;

    if (cap >= 8) {
        int* counts  = (int*)d_ws;
        int* buckets = counts + N;

        zero_kernel<<<2048, 256, 0, stream>>>(out, out_elems, counts, N);
        bucket_fill_kernel<<<(E + 255) / 256, 256, 0, stream>>>(
            targets, msgs, out, counts, buckets, E, N, cap);
        gather_kernel<<<N, 64, 0, stream>>>(msgs, counts, buckets, out, E, N, cap);
    } else {
        // tiny-workspace fallback: correctness over speed
        int* counts = (int*)d_ws;  // unused
        zero_kernel<<<2048, 256, 0, stream>>>(out, out_elems, counts, 0);
        scatter_atomic_kernel<<<4096, 256, 0, stream>>>(msgs, targets, out, E, N);
    }
}

// Round 2
// 156.477 us; speedup vs baseline: 1.0150x; 1.0150x over previous
//
#include <hip/hip_runtime.h>

// EdgeSumAggregatorSparse: out[b, t[e], d] += msgs[b, e, d]
// B=2, D=128 hard-coded; E, N derived at launch.

#define D_DIM 128
#define B_DIM 2
#define MAX_CAP 256

// ---------------------------------------------------------------- zero pass
__global__ void zero_kernel(float* __restrict__ out, size_t out_elems,
                            int* __restrict__ counts, int n_counts) {
    size_t i = (size_t)blockIdx.x * blockDim.x + threadIdx.x;
    size_t stride = (size_t)gridDim.x * blockDim.x;
    for (size_t j = i; j < out_elems; j += stride) out[j] = 0.0f;
    for (size_t j = i; j < (size_t)n_counts; j += stride) counts[j] = 0;
}

// ------------------------------------------------------------- bucket fill
// One thread per edge. Claims a slot in its target node's bucket via an int
// atomic. Overflow (> cap edges on one node) falls back to direct fp32
// atomics into out — correct for any input, ~never taken at cap=256, lambda=50.
__global__ void bucket_fill_kernel(const int* __restrict__ targets,
                                   const float* __restrict__ msgs,
                                   float* __restrict__ out,
                                   int* __restrict__ counts,
                                   int* __restrict__ buckets,
                                   int E, int N, int cap) {
    int e = blockIdx.x * blockDim.x + threadIdx.x;
    if (e >= E) return;
    int t = targets[e];
    int pos = atomicAdd(&counts[t], 1);
    if (pos < cap) {
        buckets[(size_t)t * cap + pos] = e;
    } else {
        // rare overflow path: direct scatter-add (out pre-zeroed)
        for (int b = 0; b < B_DIM; ++b) {
            const float* src = msgs + ((size_t)b * E + e) * D_DIM;
            float* dst = out + ((size_t)b * N + t) * D_DIM;
            for (int d = 0; d < D_DIM; ++d) atomicAdd(&dst[d], src[d]);
        }
    }
}

// ------------------------------------------------------------------ gather
// One block (64 threads = 1 wave) per node.
// lanes 0..31  -> batch 0, float4 slice q = lane
// lanes 32..63 -> batch 1, float4 slice q = lane-32
// Bucket entries are staged 64-at-a-time with one coalesced load, then
// broadcast via __shfl with a uniform lane index (compiles to v_readlane ->
// SGPR-based row addressing), letting the compiler pipeline several 1KB row
// loads per wave (unroll 4).
__global__ __launch_bounds__(64) void gather_kernel(
        const float* __restrict__ msgs,
        const int* __restrict__ counts,
        const int* __restrict__ buckets,
        float* __restrict__ out,
        int E, int N, int cap) {
    int n = blockIdx.x;
    int tid = threadIdx.x;
    int b = tid >> 5;    // batch
    int q = tid & 31;    // float4 slot within the 128-float row

    int cnt_raw = counts[n];
    int cnt = cnt_raw < cap ? cnt_raw : cap;
    const int* bk = buckets + (size_t)n * cap;

    float4 acc = make_float4(0.f, 0.f, 0.f, 0.f);
    const float* base = msgs + (size_t)b * E * D_DIM;

    for (int chunk = 0; chunk < cnt; chunk += 64) {
        int m = cnt - chunk;
        if (m > 64) m = 64;
        // coalesced stage of up to 64 edge ids into one register per lane
        int my_e = (tid < m) ? bk[chunk + tid] : 0;
        #pragma unroll 4
        for (int j = 0; j < m; ++j) {
            int e = __shfl(my_e, j);   // uniform j -> readlane broadcast
            const float4* row = reinterpret_cast<const float4*>(base + (size_t)e * D_DIM);
            float4 v = row[q];
            acc.x += v.x; acc.y += v.y; acc.z += v.z; acc.w += v.w;
        }
    }

    float4* o = reinterpret_cast<float4*>(out + ((size_t)b * N + n) * D_DIM) + q;
    if (cnt_raw > cap) {
        // overflow contributions already atomically added into out: RMW
        float4 cur = *o;
        cur.x += acc.x; cur.y += acc.y; cur.z += acc.z; cur.w += acc.w;
        *o = cur;
    } else {
        *o = acc;   // sole writer, out row untouched by overflow path
    }
}

// --------------------------------------------------- fallback: pure atomics
__global__ void scatter_atomic_kernel(const float* __restrict__ msgs,
                                      const int* __restrict__ targets,
                                      float* __restrict__ out,
                                      int E, int N) {
    size_t total = (size_t)E * D_DIM;
    size_t stride = (size_t)gridDim.x * blockDim.x;
    for (size_t idx = (size_t)blockIdx.x * blockDim.x + threadIdx.x;
         idx < total; idx += stride) {
        int e = (int)(idx >> 7);
        int d = (int)(idx & (D_DIM - 1));
        int t = targets[e];
        atomicAdd(&out[((size_t)0 * N + t) * D_DIM + d],
                  msgs[((size_t)0 * E + e) * D_DIM + d]);
        atomicAdd(&out[((size_t)1 * N + t) * D_DIM + d],
                  msgs[((size_t)1 * E + e) * D_DIM + d]);
    }
}

extern "C" void kernel_launch(void* const* d_in, const int* in_sizes, int n_in,
                              void* d_out, int out_size, void* d_ws, size_t ws_size,
                              hipStream_t stream) {
    const float* msgs    = (const float*)d_in[0];
    const int*   targets = (const int*)d_in[1];
    float*       out     = (float*)d_out;

    const int E = in_sizes[1];
    const int N = out_size / (B_DIM * D_DIM);

    // workspace layout: [ counts: N ints ][ buckets: N*cap ints ]
    size_t ws_ints = ws_size / sizeof(int);
    long cap_l = ((long)ws_ints - N) / (N > 0 ? N : 1);
    int cap = (int)(cap_l < 0 ? 0 : (cap_l > MAX_CAP ? MAX_CAP : cap_l));

    size_t out_elems = (size_t)out_size;

    if (cap >= 8) {
        int* counts  = (int*)d_ws;
        int* buckets = counts + N;

        zero_kernel<<<2048, 256, 0, stream>>>(out, out_elems, counts, N);
        bucket_fill_kernel<<<(E + 255) / 256, 256, 0, stream>>>(
            targets, msgs, out, counts, buckets, E, N, cap);
        gather_kernel<<<N, 64, 0, stream>>>(msgs, counts, buckets, out, E, N, cap);
    } else {
        // tiny-workspace fallback: correctness over speed
        int* counts = (int*)d_ws;  // unused
        zero_kernel<<<2048, 256, 0, stream>>>(out, out_elems, counts, 0);
        scatter_atomic_kernel<<<4096, 256, 0, stream>>>(msgs, targets, out, E, N);
    }
}